// Round 7
// baseline (273.945 us; speedup 1.0000x reference)
//
#include <hip/hip_runtime.h>
#include <hip/hip_bf16.h>
#include <cstddef>
#include <cstdint>

// ---------------------------------------------------------------------------
// Differential attention (PraxisAttention).
// Round 13: counted-vmcnt K pipeline + direct-global V + sequential fold.
//  - R7-R12 accounting: LDS pipe service (staging DMA + 16-17 b128/wave/step
//    + P round-trip) bounds every config with real occupancy; vmcnt(0) drain
//    at each barrier adds ~40% overhead. Three co-designed fixes:
//  - V^T read DIRECT global->regs (L2-hot, 16B/lane lines): deletes V LDS
//    reads, V staging DMA, 24KB LDS. V-loads issued BEFORE K-stage so the
//    compiler's vf wait is vmcnt(4), not a drain.
//  - K triple-buffered, staged 2 steps ahead; raw s_barrier + counted
//    asm s_waitcnt vmcnt(4) (m201/T3/T4 pattern) - DMA spans barriers.
//  - Sequential fold: block runs tile qtA then tile 63-qtA (32-row tiles):
//    cost = 65 steps for ALL 512 blocks -> 2 equal-lifetime blocks/CU
//    (LDS 53.9KB, launch_bounds(256,2), ~180 VGPR, no spill).
//  - Kept: exp2-domain softmax, diag-only masking, ldsP[16][36] P path,
//    setprio, head-1 epilogue handoff via ldsK alias (16KB, loop done).
// ---------------------------------------------------------------------------

typedef __bf16 bf16x8 __attribute__((ext_vector_type(8)));
typedef __bf16 bf16x4 __attribute__((ext_vector_type(4)));
typedef float f32x4 __attribute__((ext_vector_type(4)));

constexpr int SEQ = 2048;
constexpr int DH  = 128;
constexpr int NH  = 8;
constexpr int NH2 = 16;
constexpr float SCALE  = 0.088388347648318447f;  // 1/sqrt(128) (fallback path)
constexpr float QSCALE = 0.127517430f;           // log2(e)/sqrt(128) (exp2 domain)

template <bool B> struct BoolK { static constexpr bool value = B; };

// ws layout (bytes):
//   [0,256)        : stats (sum, sumsq) per (b,h)
//   [4096, +16MB)  : Kb  bf16               [b][h2][t][d]
//   [.., +8MB)     : Vtb bf16               [b][h][d][t]
constexpr size_t QK_ELEMS = (size_t)2 * NH2 * SEQ * DH;   // 8,388,608
constexpr size_t V_ELEMS  = (size_t)2 * NH  * SEQ * DH;   // 4,194,304
constexpr size_t OFF_KB   = 4096;
constexpr size_t OFF_VT   = OFF_KB + QK_ELEMS * 2;
constexpr size_t WS_NEED  = OFF_VT + V_ELEMS * 2;

__device__ __forceinline__ void load_lds16(const void* g, void* l) {
  __builtin_amdgcn_global_load_lds(
      (const __attribute__((address_space(1))) uint32_t*)g,
      (__attribute__((address_space(3))) uint32_t*)l, 16, 0, 0);
}

__device__ __forceinline__ bf16x8 cvt8(float4 a, float4 b) {
  bf16x8 r;
  r[0] = (__bf16)a.x; r[1] = (__bf16)a.y; r[2] = (__bf16)a.z; r[3] = (__bf16)a.w;
  r[4] = (__bf16)b.x; r[5] = (__bf16)b.y; r[6] = (__bf16)b.z; r[7] = (__bf16)b.w;
  return r;
}

// ---------------- fused pre-pass: K->bf16, V->V^T bf16, stats zero ---------
__global__ __launch_bounds__(256) void prep_kernel(
    const float* __restrict__ k, const float* __restrict__ v,
    __bf16* __restrict__ Kb, __bf16* __restrict__ Vtb,
    float* __restrict__ stats)
{
  __shared__ float tile[32][33];
  const int id = blockIdx.x;
  if (id == 0 && threadIdx.x < 64) stats[threadIdx.x] = 0.f;
  if (id < 4096) {
    const size_t i = ((size_t)id * 256 + threadIdx.x) * 8;
    float4 a = *(const float4*)(k + i);
    float4 b = *(const float4*)(k + i + 4);
    *(bf16x8*)(Kb + i) = cvt8(a, b);
  } else {
    const int vid = id - 4096;
    const int tt = vid & 63, dt = (vid >> 6) & 3, bh = vid >> 8;
    const int tr = threadIdx.x >> 3, tc = (threadIdx.x & 7) * 4;
    const float* src = v + ((size_t)bh * SEQ + tt * 32) * DH + dt * 32;
    float4 f = *(const float4*)(src + (size_t)tr * DH + tc);
    tile[tr][tc + 0] = f.x; tile[tr][tc + 1] = f.y;
    tile[tr][tc + 2] = f.z; tile[tr][tc + 3] = f.w;
    __syncthreads();
    __bf16* dst = Vtb + ((size_t)bh * DH + dt * 32 + tr) * SEQ + tt * 32 + tc;
    bf16x4 o;
    o[0] = (__bf16)tile[tc + 0][tr];
    o[1] = (__bf16)tile[tc + 1][tr];
    o[2] = (__bf16)tile[tc + 2][tr];
    o[3] = (__bf16)tile[tc + 3][tr];
    *(bf16x4*)dst = o;
  }
}

// ---------------- main attention kernel ------------------------------------
__global__ __launch_bounds__(256, 2) void attn3_kernel(
    const float* __restrict__ Qf, const __bf16* __restrict__ Kb,
    const __bf16* __restrict__ Vtb,
    const float* __restrict__ lq1, const float* __restrict__ lk1,
    const float* __restrict__ lq2, const float* __restrict__ lk2,
    float* __restrict__ Obuf, float* __restrict__ stats)
{
  // 53.9 KB: K tri-buf per head 48K + P 4.5K + L 128B
  __shared__ __align__(16) __bf16 ldsK[2][3][32][128];   // [grp][slot][kr][d] 48KB
  __shared__ __align__(16) __bf16 ldsP[4][16][36];       // [wave][r][c]      4.5KB
  __shared__ float ldsLa[32];                            // head-1 l

  // sequential fold: block = tiles (pair, 63-pair), cost = 65 steps, equal
  const int bid = (int)blockIdx.x;
  const int pair = bid >> 4;             // 0..31
  const int bh = bid & 15;
  const int qtA = pair, qtB = 63 - pair; // 32-row tiles
  const int b = bh >> 3, h = bh & 7;
  const int tid = threadIdx.x;
  const int wv = tid >> 6;        // wave 0..3
  const int g  = wv >> 1;         // head within pair
  const int w2 = wv & 1;          // 16-row half of the 32-row tile
  const int lane = tid & 63;
  const int l15 = lane & 15, quad = lane >> 4;

  // ---- lambda scalar ----
  float a1 = lq1[lane]*lk1[lane] + lq1[lane+64]*lk1[lane+64];
  float a2 = lq2[lane]*lk2[lane] + lq2[lane+64]*lk2[lane+64];
  #pragma unroll
  for (int off = 1; off < 64; off <<= 1) {
    a1 += __shfl_xor(a1, off);
    a2 += __shfl_xor(a2, off);
  }
  const float lam = __expf(a1) - __expf(a2) + 0.8f;

  const size_t headQK = (size_t)(b*NH2 + 2*h + g) * SEQ * DH;  // this head
  const float*  Qh  = Qf + headQK;
  const __bf16* Kh  = Kb + headQK;
  const __bf16* Vth = Vtb + (size_t)(b*NH + h) * DH * SEQ;
  const __bf16* Vlane = Vth + (size_t)l15 * SEQ + quad*8;  // + nt*16*SEQ + kbt

  // ---- K staging offsets: head g staged by its 2 waves, 4 chunks/lane ----
  int goffK[4];
  #pragma unroll
  for (int i = 0; i < 4; ++i) {
    const int c  = i*128 + w2*64 + lane;   // flat chunk 0..511
    const int R  = c >> 4, cs = c & 15;
    goffK[i] = R * DH + ((cs ^ (R & 15)) * 8);
  }
  __bf16* ldsKg = &ldsK[g][0][0][0];

  const int nA = qtA + 1;
  const int total = nA + qtB + 1;        // 65 for every block
  const int rbA = qtA*32 + w2*16;
  const int rbB = qtB*32 + w2*16;

  // Q fragments for both tiles: fp32 -> exp2-domain scale -> bf16
  bf16x8 qfA[4], qfB[4];
  {
    const float* srcA = Qh + (size_t)(rbA + l15)*DH + quad*8;
    const float* srcB = Qh + (size_t)(rbB + l15)*DH + quad*8;
    #pragma unroll
    for (int kd = 0; kd < 4; ++kd) {
      float4 f0 = *(const float4*)(srcA + kd*32);
      float4 f1 = *(const float4*)(srcA + kd*32 + 4);
      f0.x *= QSCALE; f0.y *= QSCALE; f0.z *= QSCALE; f0.w *= QSCALE;
      f1.x *= QSCALE; f1.y *= QSCALE; f1.z *= QSCALE; f1.w *= QSCALE;
      qfA[kd] = cvt8(f0, f1);
      float4 g0 = *(const float4*)(srcB + kd*32);
      float4 g1 = *(const float4*)(srcB + kd*32 + 4);
      g0.x *= QSCALE; g0.y *= QSCALE; g0.z *= QSCALE; g0.w *= QSCALE;
      g1.x *= QSCALE; g1.y *= QSCALE; g1.z *= QSCALE; g1.w *= QSCALE;
      qfB[kd] = cvt8(g0, g1);
    }
  }

  f32x4 oaccA[8], oaccB[8];
  float lsA[4] = {0.f,0.f,0.f,0.f}, lsB[4] = {0.f,0.f,0.f,0.f};
  #pragma unroll
  for (int nt = 0; nt < 8; ++nt) {
    oaccA[nt] = (f32x4){0.f,0.f,0.f,0.f};
    oaccB[nt] = (f32x4){0.f,0.f,0.f,0.f};
  }

  auto stageK = [&](int f) {
    const int kb = (f < nA ? f : f - nA) * 32;
    const int slot = f % 3;
    const __bf16* src = Kh + (size_t)kb * DH;
    __bf16* dst = ldsKg + slot*4096;
    #pragma unroll
    for (int i = 0; i < 4; ++i)
      load_lds16(src + goffK[i], dst + i*1024 + w2*512);
  };

  // softmax: p = exp2(s), mask only on diagonal step, accumulate l, -> ldsP
  auto sm_body = [&](const f32x4& s0, const f32x4& s1, float (&ls)[4],
                     const int rb, const int kbt, auto MASKC) {
    constexpr bool MASKED = decltype(MASKC)::value;
    #pragma unroll
    for (int r = 0; r < 4; ++r) {
      float p0 = __builtin_amdgcn_exp2f(s0[r]);
      float p1 = __builtin_amdgcn_exp2f(s1[r]);
      if constexpr (MASKED) {
        const int qr = rb + quad*4 + r;
        if (kbt + l15      > qr) p0 = 0.f;
        if (kbt + l15 + 16 > qr) p1 = 0.f;
      }
      ls[r] += p0 + p1;
      ldsP[wv][quad*4 + r][l15]      = (__bf16)p0;
      ldsP[wv][quad*4 + r][l15 + 16] = (__bf16)p1;
    }
  };

  // one step's compute for one tile (refs keep all indexing compile-time)
  auto step_body = [&](bf16x8 (&qf)[4], f32x4 (&oacc)[8], float (&ls)[4],
                       const int rb, const bool diag, const int kbt,
                       const int slot, bf16x8 (&vf)[8]) {
    f32x4 sacc[2];
    sacc[0] = (f32x4){0.f,0.f,0.f,0.f};
    sacc[1] = (f32x4){0.f,0.f,0.f,0.f};
    __builtin_amdgcn_s_setprio(1);
    #pragma unroll
    for (int n = 0; n < 2; ++n)
      #pragma unroll
      for (int kd = 0; kd < 4; ++kd) {
        bf16x8 kf = *(const bf16x8*)&ldsK[g][slot][n*16 + l15][((kd*4 + quad) ^ l15) * 8];
        sacc[n] = __builtin_amdgcn_mfma_f32_16x16x32_bf16(qf[kd], kf, sacc[n], 0, 0, 0);
      }
    __builtin_amdgcn_s_setprio(0);

    if (diag) sm_body(sacc[0], sacc[1], ls, rb, kbt, BoolK<true>{});
    else      sm_body(sacc[0], sacc[1], ls, rb, kbt, BoolK<false>{});

    bf16x8 pf = *(const bf16x8*)&ldsP[wv][l15][quad*8];
    __builtin_amdgcn_s_setprio(1);
    #pragma unroll
    for (int nt = 0; nt < 8; ++nt)
      oacc[nt] = __builtin_amdgcn_mfma_f32_16x16x32_bf16(pf, vf[nt], oacc[nt], 0, 0, 0);
    __builtin_amdgcn_s_setprio(0);
  };

  // ---- prologue: stage K for steps 0 and 1 --------------------------------
  stageK(0);
  stageK(1);
  asm volatile("s_waitcnt vmcnt(4)" ::: "memory");   // step-0 K landed
  __builtin_amdgcn_sched_barrier(0);
  __builtin_amdgcn_s_barrier();
  __builtin_amdgcn_sched_barrier(0);

  for (int f = 0; f < total; ++f) {
    const int slot = f % 3;
    const bool isA = f < nA;
    const int kbt = (isA ? f : f - nA) * 32;
    const bool more = (f + 2) < total;

    // V for THIS step: direct global->reg (issued before K-stage so the
    // compiler's vf wait is a counted vmcnt, not a drain)
    bf16x8 vf[8];
    #pragma unroll
    for (int nt = 0; nt < 8; ++nt)
      vf[nt] = *(const bf16x8*)(Vlane + (size_t)nt*16*SEQ + kbt);
    __builtin_amdgcn_sched_barrier(0);

    if (more) stageK(f + 2);
    __builtin_amdgcn_sched_barrier(0);

    if (isA) step_body(qfA, oaccA, lsA, rbA, f == qtA,      kbt, slot, vf);
    else     step_body(qfB, oaccB, lsB, rbB, f == total - 1, kbt, slot, vf);

    // next step reads K buf (f+1)%3: require its DMA (issued last iter) done;
    // K(f+2) (4 loads, newest) may stay in flight across the barrier.
    if (more) { asm volatile("s_waitcnt vmcnt(4)" ::: "memory"); }
    else      { asm volatile("s_waitcnt vmcnt(0)" ::: "memory"); }
    __builtin_amdgcn_sched_barrier(0);
    __builtin_amdgcn_s_barrier();
    __builtin_amdgcn_sched_barrier(0);
  }

  // ---- epilogues (loop done; ldsK reusable as 16KB scratch) ---------------
  float osum = 0.f, oss = 0.f;
  float* Oscr = (float*)&ldsK[0][0][0][0];
  float* obase = Obuf + (size_t)(b*NH + h) * SEQ * DH;

  auto epi = [&](f32x4 (&oacc)[8], float (&ls)[4], const int qt) {
    float lr[4];
    #pragma unroll
    for (int r = 0; r < 4; ++r) {
      float v = ls[r];
      #pragma unroll
      for (int off = 1; off < 16; off <<= 1) v += __shfl_xor(v, off);
      lr[r] = v;
    }
    __builtin_amdgcn_s_barrier();        // scratch free (prev users done)
    if (g == 1) {
      #pragma unroll
      for (int nt = 0; nt < 8; ++nt)
        #pragma unroll
        for (int r = 0; r < 4; ++r)
          Oscr[(w2*16 + quad*4 + r)*128 + nt*16 + l15] = oacc[nt][r];
      if (l15 == 0) {
        #pragma unroll
        for (int r = 0; r < 4; ++r)
          ldsLa[w2*16 + quad*4 + r] = lr[r];
      }
    }
    asm volatile("s_waitcnt lgkmcnt(0)" ::: "memory");  // raw barrier: drain writes
    __builtin_amdgcn_s_barrier();
    if (g == 0) {
      #pragma unroll
      for (int r = 0; r < 4; ++r) {
        const int row = w2*16 + quad*4 + r;
        const float l0 = lr[r] + 1.0f;
        const float l1 = ldsLa[row] + 1.0f;
        const float i0 = 1.0f / l0;
        const float i1 = lam / l1;
        float* orow = obase + (size_t)(qt*32 + row) * DH + l15;
        #pragma unroll
        for (int nt = 0; nt < 8; ++nt) {
          const float o1 = Oscr[row*128 + nt*16 + l15];
          const float val = oacc[nt][r] * i0 - o1 * i1;
          orow[nt*16] = val;
          osum += val;
          oss  += val * val;
        }
      }
    }
  };

  epi(oaccA, lsA, qtA);
  epi(oaccB, lsB, qtB);

  #pragma unroll
  for (int off = 1; off < 64; off <<= 1) {
    osum += __shfl_xor(osum, off);
    oss  += __shfl_xor(oss, off);
  }
  if (g == 0 && lane == 0) {
    atomicAdd(&stats[2*(b*NH + h)],     osum);
    atomicAdd(&stats[2*(b*NH + h) + 1], oss);
  }
}

// ---------------- fallback (round-1) attention kernel ----------------------
__global__ __launch_bounds__(256) void attn_fb_kernel(
    const float* __restrict__ q, const float* __restrict__ k,
    const float* __restrict__ v,
    const float* __restrict__ lq1, const float* __restrict__ lk1,
    const float* __restrict__ lq2, const float* __restrict__ lk2,
    float* __restrict__ Obuf, float* __restrict__ stats)
{
  __shared__ __align__(16) __bf16 lds_k[2][32][136];
  __shared__ __align__(16) __bf16 lds_vt[128][40];
  __shared__ __align__(16) __bf16 lds_p[4][2][16][40];

  const int qt = blockIdx.x, h = blockIdx.y, b = blockIdx.z;
  const int qb = qt * 64;
  const int tid = threadIdx.x;
  const int w = tid >> 6, lane = tid & 63;
  const int l15 = lane & 15, quad = lane >> 4;

  float a1 = lq1[lane]*lk1[lane] + lq1[lane+64]*lk1[lane+64];
  float a2 = lq2[lane]*lk2[lane] + lq2[lane+64]*lk2[lane+64];
  #pragma unroll
  for (int off = 1; off < 64; off <<= 1) {
    a1 += __shfl_xor(a1, off);
    a2 += __shfl_xor(a2, off);
  }
  const float lam = __expf(a1) - __expf(a2) + 0.8f;

  const float* qh0 = q + (size_t)(b*NH2 + 2*h) * SEQ * DH;
  const float* qh1 = qh0 + (size_t)SEQ * DH;
  const float* kh0 = k + (size_t)(b*NH2 + 2*h) * SEQ * DH;
  const float* kh1 = kh0 + (size_t)SEQ * DH;
  const float* vh  = v + (size_t)(b*NH + h) * SEQ * DH;

  bf16x8 qf[2][4];
  {
    const int qrow = qb + w*16 + l15;
    #pragma unroll
    for (int sh = 0; sh < 2; ++sh) {
      const float* src = (sh ? qh1 : qh0) + (size_t)qrow * DH + quad*8;
      #pragma unroll
      for (int kd = 0; kd < 4; ++kd) {
        float4 f0 = *(const float4*)(src + kd*32);
        float4 f1 = *(const float4*)(src + kd*32 + 4);
        qf[sh][kd] = cvt8(f0, f1);
      }
    }
  }

  f32x4 oacc[2][8];
  #pragma unroll
  for (int sh = 0; sh < 2; ++sh)
    #pragma unroll
    for (int nt = 0; nt < 8; ++nt)
      oacc[sh][nt] = (f32x4){0.f,0.f,0.f,0.f};

  float mst[2][4] = {{0.f,0.f,0.f,0.f},{0.f,0.f,0.f,0.f}};
  float lst[2][4] = {{1.f,1.f,1.f,1.f},{1.f,1.f,1.f,1.f}};

  const int krow = tid >> 2, ksh = krow >> 5, kr = krow & 31;
  const int kd0 = (tid & 3) * 32;
  const float* ksrc0 = (ksh ? kh1 : kh0) + kd0;
  const int vt = tid >> 3, vd = (tid & 7) * 16;

  const int nsteps = (qb + 64) / 32;
  for (int st = 0; st < nsteps; ++st) {
    const int kbt = st * 32;
    {
      const float* sp = ksrc0 + (size_t)(kbt + kr) * DH;
      #pragma unroll
      for (int c = 0; c < 4; ++c) {
        float4 f0 = *(const float4*)(sp + c*8);
        float4 f1 = *(const float4*)(sp + c*8 + 4);
        *(bf16x8*)&lds_k[ksh][kr][kd0 + c*8] = cvt8(f0, f1);
      }
      const float* vp = vh + (size_t)(kbt + vt) * DH + vd;
      #pragma unroll
      for (int c = 0; c < 4; ++c) {
        float4 f = *(const float4*)(vp + c*4);
        lds_vt[vd + c*4 + 0][vt] = (__bf16)f.x;
        lds_vt[vd + c*4 + 1][vt] = (__bf16)f.y;
        lds_vt[vd + c*4 + 2][vt] = (__bf16)f.z;
        lds_vt[vd + c*4 + 3][vt] = (__bf16)f.w;
      }
    }
    __syncthreads();

    f32x4 sacc[2][2];
    #pragma unroll
    for (int sh = 0; sh < 2; ++sh)
      #pragma unroll
      for (int n = 0; n < 2; ++n)
        sacc[sh][n] = (f32x4){0.f,0.f,0.f,0.f};

    #pragma unroll
    for (int sh = 0; sh < 2; ++sh)
      #pragma unroll
      for (int n = 0; n < 2; ++n)
        #pragma unroll
        for (int kd = 0; kd < 4; ++kd) {
          bf16x8 bf = *(const bf16x8*)&lds_k[sh][n*16 + l15][kd*32 + quad*8];
          sacc[sh][n] = __builtin_amdgcn_mfma_f32_16x16x32_bf16(qf[sh][kd], bf, sacc[sh][n], 0, 0, 0);
        }

    const int qrow0 = qb + w*16 + quad*4;
    const int c0 = kbt + l15, c1 = c0 + 16;
    #pragma unroll
    for (int sh = 0; sh < 2; ++sh) {
      #pragma unroll
      for (int r = 0; r < 4; ++r) {
        float s0 = sacc[sh][0][r] * SCALE;
        float s1 = sacc[sh][1][r] * SCALE;
        const int qr = qrow0 + r;
        if (c0 > qr) s0 = -1e30f;
        if (c1 > qr) s1 = -1e30f;
        float mx = fmaxf(s0, s1);
        #pragma unroll
        for (int off = 1; off < 16; off <<= 1)
          mx = fmaxf(mx, __shfl_xor(mx, off));
        const float mnew = fmaxf(mst[sh][r], mx);
        const float alpha = __expf(mst[sh][r] - mnew);
        mst[sh][r] = mnew;
        const float p0 = __expf(s0 - mnew);
        const float p1 = __expf(s1 - mnew);
        float rs = p0 + p1;
        #pragma unroll
        for (int off = 1; off < 16; off <<= 1)
          rs += __shfl_xor(rs, off);
        lst[sh][r] = lst[sh][r] * alpha + rs;
        #pragma unroll
        for (int nt = 0; nt < 8; ++nt)
          oacc[sh][nt][r] *= alpha;
        lds_p[w][sh][quad*4 + r][l15]      = (__bf16)p0;
        lds_p[w][sh][quad*4 + r][l15 + 16] = (__bf16)p1;
      }
    }

    {
      bf16x8 pf0 = *(const bf16x8*)&lds_p[w][0][l15][quad*8];
      bf16x8 pf1 = *(const bf16x8*)&lds_p[w][1][l15][quad*8];
      #pragma unroll
      for (int nt = 0; nt < 8; ++nt) {
        bf16x8 vf = *(const bf16x8*)&lds_vt[nt*16 + l15][quad*8];
        oacc[0][nt] = __builtin_amdgcn_mfma_f32_16x16x32_bf16(pf0, vf, oacc[0][nt], 0, 0, 0);
        oacc[1][nt] = __builtin_amdgcn_mfma_f32_16x16x32_bf16(pf1, vf, oacc[1][nt], 0, 0, 0);
      }
    }
    __syncthreads();
  }

  const int qrow0 = qb + w*16 + quad*4;
  float* obase = Obuf + (size_t)(b*NH + h) * SEQ * DH;
  float sum = 0.f, ss = 0.f;
  #pragma unroll
  for (int r = 0; r < 4; ++r) {
    const float i0 = 1.0f / lst[0][r];
    const float i1 = lam / lst[1][r];
    float* orow = obase + (size_t)(qrow0 + r) * DH + l15;
    #pragma unroll
    for (int nt = 0; nt < 8; ++nt) {
      const float val = oacc[0][nt][r] * i0 - oacc[1][nt][r] * i1;
      orow[nt*16] = val;
      sum += val;
      ss  += val * val;
    }
  }
  #pragma unroll
  for (int off = 1; off < 64; off <<= 1) {
    sum += __shfl_xor(sum, off);
    ss  += __shfl_xor(ss, off);
  }
  if (lane == 0) {
    atomicAdd(&stats[2*(b*NH + h)],     sum);
    atomicAdd(&stats[2*(b*NH + h) + 1], ss);
  }
}

// ---------------- GroupNorm epilogue ---------------------------------------
__global__ __launch_bounds__(256) void norm_kernel(
    float* __restrict__ Obuf, const float* __restrict__ stats,
    const float* __restrict__ gw, const float* __restrict__ gb)
{
  const int idx = (blockIdx.x * 256 + threadIdx.x) * 4;
  const int bh = idx >> 18;
  const int local = idx & 262143;
  const float inv = 1.0f / 262144.0f;
  const float mean = stats[2*bh] * inv;
  const float var  = stats[2*bh + 1] * inv - mean * mean;
  const float rstd = rsqrtf(var + 1e-5f);
  const int c = ((bh & 7) << 7) + (local >> 11);
  const float wq = gw[c] * rstd;
  const float bq = gb[c];
  float4 o = *(const float4*)(Obuf + idx);
  float4 r;
  r.x = ((o.x - mean) * wq + bq) * 0.2f;
  r.y = ((o.y - mean) * wq + bq) * 0.2f;
  r.z = ((o.z - mean) * wq + bq) * 0.2f;
  r.w = ((o.w - mean) * wq + bq) * 0.2f;
  *(float4*)(Obuf + idx) = r;
}

extern "C" void kernel_launch(void* const* d_in, const int* in_sizes, int n_in,
                              void* d_out, int out_size, void* d_ws, size_t ws_size,
                              hipStream_t stream) {
  const float* q   = (const float*)d_in[0];
  const float* k   = (const float*)d_in[1];
  const float* v   = (const float*)d_in[2];
  const float* lq1 = (const float*)d_in[3];
  const float* lk1 = (const float*)d_in[4];
  const float* lq2 = (const float*)d_in[5];
  const float* lk2 = (const float*)d_in[6];
  const float* gw  = (const float*)d_in[7];
  const float* gb  = (const float*)d_in[8];
  float* out = (float*)d_out;
  float* stats = (float*)d_ws;

  if (ws_size >= WS_NEED) {
    __bf16* Kb  = (__bf16*)((char*)d_ws + OFF_KB);
    __bf16* Vtb = (__bf16*)((char*)d_ws + OFF_VT);

    prep_kernel<<<8192, 256, 0, stream>>>(k, v, Kb, Vtb, stats);

    attn3_kernel<<<512, 256, 0, stream>>>(q, Kb, Vtb,
        lq1, lk1, lq2, lk2, out, stats);
  } else {
    (void)hipMemsetAsync(d_ws, 0, 256, stream);
    attn_fb_kernel<<<dim3(32, NH, 2), 256, 0, stream>>>(q, k, v,
        lq1, lk1, lq2, lk2, out, stats);
  }

  const int total = 2 * NH * SEQ * DH;
  norm_kernel<<<total / 1024, 256, 0, stream>>>(out, stats, gw, gb);
}

// Round 8
// 203.608 us; speedup vs baseline: 1.3455x; 1.3455x over previous
//
#include <hip/hip_runtime.h>
#include <hip/hip_bf16.h>
#include <cstddef>
#include <cstdint>

// ---------------------------------------------------------------------------
// Differential attention (PraxisAttention).
// FINAL (consolidation of Round 9 — measured best: attn3 ~89us, total 203.4us).
// Structure: head-split groups, 512 threads = 2 groups x 4 waves; group g
// owns head 2h+g entirely. K dbuf per group + V dbuf shared (global_load_lds,
// XOR-swizzled). exp2-domain softmax (log2e folded into Q prescale), masking
// only on diagonal K-steps, setprio around MFMA clusters, fixed-m ghostmax.
// Complementary-pair grid (bid c / c+256 costs sum to 68 -> equalized CU
// finish times). LDS 57.5KB -> 2 blocks/CU capacity.
// Post-session verdict: with >=8 resident waves the kernel is LDS-pipe
// service-bound (~1650cy/step matches measured phase time); wide-wave /
// swapped-QK / counted-vmcnt / LPT variants all regressed (R10-R13).
// ---------------------------------------------------------------------------

typedef __bf16 bf16x8 __attribute__((ext_vector_type(8)));
typedef __bf16 bf16x4 __attribute__((ext_vector_type(4)));
typedef float f32x4 __attribute__((ext_vector_type(4)));

constexpr int SEQ = 2048;
constexpr int DH  = 128;
constexpr int NH  = 8;
constexpr int NH2 = 16;
constexpr float SCALE  = 0.088388347648318447f;  // 1/sqrt(128) (fallback path)
constexpr float QSCALE = 0.127517430f;           // log2(e)/sqrt(128) (exp2 domain)

template <bool B> struct BoolK { static constexpr bool value = B; };

// ws layout (bytes):
//   [0,256)        : stats (sum, sumsq) per (b,h)
//   [4096, +16MB)  : Kb  bf16               [b][h2][t][d]
//   [.., +8MB)     : Vtb bf16               [b][h][d][t]
constexpr size_t QK_ELEMS = (size_t)2 * NH2 * SEQ * DH;   // 8,388,608
constexpr size_t V_ELEMS  = (size_t)2 * NH  * SEQ * DH;   // 4,194,304
constexpr size_t OFF_KB   = 4096;
constexpr size_t OFF_VT   = OFF_KB + QK_ELEMS * 2;
constexpr size_t WS_NEED  = OFF_VT + V_ELEMS * 2;

__device__ __forceinline__ void load_lds16(const void* g, void* l) {
  __builtin_amdgcn_global_load_lds(
      (const __attribute__((address_space(1))) uint32_t*)g,
      (__attribute__((address_space(3))) uint32_t*)l, 16, 0, 0);
}

__device__ __forceinline__ bf16x8 cvt8(float4 a, float4 b) {
  bf16x8 r;
  r[0] = (__bf16)a.x; r[1] = (__bf16)a.y; r[2] = (__bf16)a.z; r[3] = (__bf16)a.w;
  r[4] = (__bf16)b.x; r[5] = (__bf16)b.y; r[6] = (__bf16)b.z; r[7] = (__bf16)b.w;
  return r;
}

// ---------------- fused pre-pass: K->bf16, V->V^T bf16, stats zero ---------
__global__ __launch_bounds__(256) void prep_kernel(
    const float* __restrict__ k, const float* __restrict__ v,
    __bf16* __restrict__ Kb, __bf16* __restrict__ Vtb,
    float* __restrict__ stats)
{
  __shared__ float tile[32][33];
  const int id = blockIdx.x;
  if (id == 0 && threadIdx.x < 64) stats[threadIdx.x] = 0.f;
  if (id < 4096) {
    const size_t i = ((size_t)id * 256 + threadIdx.x) * 8;
    float4 a = *(const float4*)(k + i);
    float4 b = *(const float4*)(k + i + 4);
    *(bf16x8*)(Kb + i) = cvt8(a, b);
  } else {
    const int vid = id - 4096;
    const int tt = vid & 63, dt = (vid >> 6) & 3, bh = vid >> 8;
    const int tr = threadIdx.x >> 3, tc = (threadIdx.x & 7) * 4;
    const float* src = v + ((size_t)bh * SEQ + tt * 32) * DH + dt * 32;
    float4 f = *(const float4*)(src + (size_t)tr * DH + tc);
    tile[tr][tc + 0] = f.x; tile[tr][tc + 1] = f.y;
    tile[tr][tc + 2] = f.z; tile[tr][tc + 3] = f.w;
    __syncthreads();
    __bf16* dst = Vtb + ((size_t)bh * DH + dt * 32 + tr) * SEQ + tt * 32 + tc;
    bf16x4 o;
    o[0] = (__bf16)tile[tc + 0][tr];
    o[1] = (__bf16)tile[tc + 1][tr];
    o[2] = (__bf16)tile[tc + 2][tr];
    o[3] = (__bf16)tile[tc + 3][tr];
    *(bf16x4*)dst = o;
  }
}

// ---------------- main attention kernel (head-split, 2 blocks/CU) ----------
__global__ __launch_bounds__(512, 4) void attn3_kernel(
    const float* __restrict__ Qf, const __bf16* __restrict__ Kb,
    const __bf16* __restrict__ Vtb,
    const float* __restrict__ lq1, const float* __restrict__ lk1,
    const float* __restrict__ lq2, const float* __restrict__ lk2,
    float* __restrict__ Obuf, float* __restrict__ stats)
{
  // 57.5 KB: K dbuf per group 32K + V dbuf shared 16K + P 9K
  __shared__ __align__(16) __bf16 ldsK[2][2][32][128];   // [grp][buf][kr][d] 32KB
  __shared__ __align__(16) __bf16 ldsVt[2][128][32];     // [buf][d][t]       16KB
  __shared__ __align__(16) __bf16 ldsP[2][4][16][36];    // [grp][wave][r][c]  9KB

  // bid remap: bids c and c+256 have phase counts summing to 34
  const int bid = (int)blockIdx.x;
  int qt, bh;
  if (bid < 256) { qt = 31 - (bid >> 4); bh = bid & 15; }
  else           { qt = (bid - 256) >> 4; bh = bid & 15; }
  const int b = bh >> 3, h = bh & 7;
  const int tid = threadIdx.x;
  const int g  = tid >> 8;        // group = head within pair (sh)
  const int t2 = tid & 255;
  const int w  = t2 >> 6;         // wave within group 0..3
  const int ws = tid >> 6;        // global wave 0..7
  const int lane = tid & 63;
  const int l15 = lane & 15, quad = lane >> 4;

  // ---- lambda scalar ----
  float a1 = lq1[lane]*lk1[lane] + lq1[lane+64]*lk1[lane+64];
  float a2 = lq2[lane]*lk2[lane] + lq2[lane+64]*lk2[lane+64];
  #pragma unroll
  for (int off = 1; off < 64; off <<= 1) {
    a1 += __shfl_xor(a1, off);
    a2 += __shfl_xor(a2, off);
  }
  const float lam = __expf(a1) - __expf(a2) + 0.8f;

  const size_t headQK = (size_t)(b*NH2 + 2*h + g) * SEQ * DH;  // this group's head
  const float*  Qh  = Qf + headQK;
  const __bf16* Kh  = Kb + headQK;
  const __bf16* Vth = Vtb + (size_t)(b*NH + h) * DH * SEQ;

  // ---- per-lane staging source offsets (element units, swizzled) ----
  // K: 2 loads/lane, rows R = w*8 + i*4 + quad (0..31), 16 chunks of 8 elems
  size_t goffK[2];
  #pragma unroll
  for (int i = 0; i < 2; ++i) {
    const int R  = w*8 + i*4 + quad;
    const int cs = lane & 15;
    goffK[i] = (size_t)R * DH + ((cs ^ (R & 15)) * 8);
  }
  // V: 1 load/lane (all 8 waves), rows d = ws*16 + (lane>>2), 4 chunks of 8 t
  const int vd = ws*16 + (lane >> 2);
  const size_t goffV = (size_t)vd * SEQ + (((lane & 3) ^ (vd & 3)) * 8);

  __bf16* ldsKg = &ldsK[g][0][0][0];
  __bf16* ldsVb = &ldsVt[0][0][0];

  const int qb = qt * 64;
  const int nsteps = 2*qt + 2;   // K-steps of 32, lockstep for both groups

  // Q fragments: fp32 global -> scale(exp2 domain) -> bf16 A-layout
  const int qrow = qb + w*16 + l15;
  bf16x8 qf[4];
  {
    const float* src = Qh + (size_t)qrow*DH + quad*8;
    #pragma unroll
    for (int kd = 0; kd < 4; ++kd) {
      float4 f0 = *(const float4*)(src + kd*32);
      float4 f1 = *(const float4*)(src + kd*32 + 4);
      f0.x *= QSCALE; f0.y *= QSCALE; f0.z *= QSCALE; f0.w *= QSCALE;
      f1.x *= QSCALE; f1.y *= QSCALE; f1.z *= QSCALE; f1.w *= QSCALE;
      qf[kd] = cvt8(f0, f1);
    }
  }

  f32x4 oacc[8];
  float lsum[4];
  #pragma unroll
  for (int nt = 0; nt < 8; ++nt) oacc[nt] = (f32x4){0.f,0.f,0.f,0.f};
  #pragma unroll
  for (int r = 0; r < 4; ++r) lsum[r] = 0.f;

  // stage step 0 into buf 0
  {
    #pragma unroll
    for (int i = 0; i < 2; ++i)
      load_lds16(Kh + goffK[i], ldsKg + w*1024 + i*512);
    load_lds16(Vth + goffV, ldsVb + ws*512);
  }
  __syncthreads();

  for (int st = 0; st < nsteps; ++st) {
    const int cur = st & 1;
    const int kbt = st * 32;

    // async prefetch next step into other buffer
    if (st + 1 < nsteps) {
      const int nxt = cur ^ 1;
      const __bf16* kg = Kh + (size_t)(kbt + 32) * DH;
      #pragma unroll
      for (int i = 0; i < 2; ++i)
        load_lds16(kg + goffK[i], ldsKg + nxt*4096 + w*1024 + i*512);
      load_lds16(Vth + (kbt + 32) + goffV, ldsVb + nxt*4096 + ws*512);
    }

    // ---- S = Q K^T ----
    f32x4 sacc[2];
    sacc[0] = (f32x4){0.f,0.f,0.f,0.f};
    sacc[1] = (f32x4){0.f,0.f,0.f,0.f};
    __builtin_amdgcn_s_setprio(1);
    #pragma unroll
    for (int n = 0; n < 2; ++n)
      #pragma unroll
      for (int kd = 0; kd < 4; ++kd) {
        bf16x8 kf = *(const bf16x8*)&ldsK[g][cur][n*16 + l15][((kd*4 + quad) ^ l15) * 8];
        sacc[n] = __builtin_amdgcn_mfma_f32_16x16x32_bf16(qf[kd], kf, sacc[n], 0, 0, 0);
      }
    __builtin_amdgcn_s_setprio(0);

    // ---- fixed-m ghostmax: p = exp2(s) (masked only on diagonal steps) ----
    const int qrow0 = qb + w*16 + quad*4;
    auto sm_body = [&](auto MASKC) {
      constexpr bool MASKED = decltype(MASKC)::value;
      #pragma unroll
      for (int r = 0; r < 4; ++r) {
        float p0 = __builtin_amdgcn_exp2f(sacc[0][r]);
        float p1 = __builtin_amdgcn_exp2f(sacc[1][r]);
        if constexpr (MASKED) {
          const int qr = qrow0 + r;
          if (kbt + l15      > qr) p0 = 0.f;
          if (kbt + l15 + 16 > qr) p1 = 0.f;
        }
        lsum[r] += p0 + p1;
        ldsP[g][w][quad*4 + r][l15]      = (__bf16)p0;
        ldsP[g][w][quad*4 + r][l15 + 16] = (__bf16)p1;
      }
    };
    if (kbt + 31 <= qb + w*16) sm_body(BoolK<false>{});
    else                       sm_body(BoolK<true>{});

    // ---- O += P V ----
    {
      bf16x8 pf = *(const bf16x8*)&ldsP[g][w][l15][quad*8];
      __builtin_amdgcn_s_setprio(1);
      #pragma unroll
      for (int nt = 0; nt < 8; ++nt) {
        bf16x8 vf = *(const bf16x8*)&ldsVt[cur][nt*16 + l15][(quad ^ (l15 & 3)) * 8];
        oacc[nt] = __builtin_amdgcn_mfma_f32_16x16x32_bf16(pf, vf, oacc[nt], 0, 0, 0);
      }
      __builtin_amdgcn_s_setprio(0);
    }
    // drains this phase's DMA; cur buffers consumed
    __syncthreads();
  }

  // ---- epilogue: group 1 hands off complete (oacc, l) for its head -------
  float lr[4];
  #pragma unroll
  for (int r = 0; r < 4; ++r) {
    float vsum = lsum[r];
    #pragma unroll
    for (int off = 1; off < 16; off <<= 1) vsum += __shfl_xor(vsum, off);
    lr[r] = vsum;
  }

  float* Oscr  = (float*)&ldsK[0][0][0][0];   // 32 KB = 64 rows x 128 f32
  float* ldsLa = (float*)&ldsP[0][0][0][0];   // 64 floats
  if (g == 1) {
    #pragma unroll
    for (int nt = 0; nt < 8; ++nt)
      #pragma unroll
      for (int r = 0; r < 4; ++r)
        Oscr[(w*16 + quad*4 + r)*128 + nt*16 + l15] = oacc[nt][r];
    if (l15 == 0) {
      #pragma unroll
      for (int r = 0; r < 4; ++r)
        ldsLa[w*16 + quad*4 + r] = lr[r];
    }
  }
  __syncthreads();

  if (g == 0) {
    const int qrow0 = qb + w*16 + quad*4;
    float* obase = Obuf + (size_t)(b*NH + h) * SEQ * DH;
    float sum = 0.f, ss = 0.f;
    #pragma unroll
    for (int r = 0; r < 4; ++r) {
      const float l0 = lr[r] + 1.0f;
      const float l1 = ldsLa[w*16 + quad*4 + r] + 1.0f;
      const float i0 = 1.0f / l0;
      const float i1 = lam / l1;
      float* orow = obase + (size_t)(qrow0 + r) * DH + l15;
      #pragma unroll
      for (int nt = 0; nt < 8; ++nt) {
        const float o1 = Oscr[(w*16 + quad*4 + r)*128 + nt*16 + l15];
        const float val = oacc[nt][r] * i0 - o1 * i1;
        orow[nt*16] = val;
        sum += val;
        ss  += val * val;
      }
    }
    #pragma unroll
    for (int off = 1; off < 64; off <<= 1) {
      sum += __shfl_xor(sum, off);
      ss  += __shfl_xor(ss, off);
    }
    if (lane == 0) {
      atomicAdd(&stats[2*(b*NH + h)],     sum);
      atomicAdd(&stats[2*(b*NH + h) + 1], ss);
    }
  }
}

// ---------------- fallback (round-1) attention kernel ----------------------
__global__ __launch_bounds__(256) void attn_fb_kernel(
    const float* __restrict__ q, const float* __restrict__ k,
    const float* __restrict__ v,
    const float* __restrict__ lq1, const float* __restrict__ lk1,
    const float* __restrict__ lq2, const float* __restrict__ lk2,
    float* __restrict__ Obuf, float* __restrict__ stats)
{
  __shared__ __align__(16) __bf16 lds_k[2][32][136];
  __shared__ __align__(16) __bf16 lds_vt[128][40];
  __shared__ __align__(16) __bf16 lds_p[4][2][16][40];

  const int qt = blockIdx.x, h = blockIdx.y, b = blockIdx.z;
  const int qb = qt * 64;
  const int tid = threadIdx.x;
  const int w = tid >> 6, lane = tid & 63;
  const int l15 = lane & 15, quad = lane >> 4;

  float a1 = lq1[lane]*lk1[lane] + lq1[lane+64]*lk1[lane+64];
  float a2 = lq2[lane]*lk2[lane] + lq2[lane+64]*lk2[lane+64];
  #pragma unroll
  for (int off = 1; off < 64; off <<= 1) {
    a1 += __shfl_xor(a1, off);
    a2 += __shfl_xor(a2, off);
  }
  const float lam = __expf(a1) - __expf(a2) + 0.8f;

  const float* qh0 = q + (size_t)(b*NH2 + 2*h) * SEQ * DH;
  const float* qh1 = qh0 + (size_t)SEQ * DH;
  const float* kh0 = k + (size_t)(b*NH2 + 2*h) * SEQ * DH;
  const float* kh1 = kh0 + (size_t)SEQ * DH;
  const float* vh  = v + (size_t)(b*NH + h) * SEQ * DH;

  bf16x8 qf[2][4];
  {
    const int qrow = qb + w*16 + l15;
    #pragma unroll
    for (int sh = 0; sh < 2; ++sh) {
      const float* src = (sh ? qh1 : qh0) + (size_t)qrow * DH + quad*8;
      #pragma unroll
      for (int kd = 0; kd < 4; ++kd) {
        float4 f0 = *(const float4*)(src + kd*32);
        float4 f1 = *(const float4*)(src + kd*32 + 4);
        qf[sh][kd] = cvt8(f0, f1);
      }
    }
  }

  f32x4 oacc[2][8];
  #pragma unroll
  for (int sh = 0; sh < 2; ++sh)
    #pragma unroll
    for (int nt = 0; nt < 8; ++nt)
      oacc[sh][nt] = (f32x4){0.f,0.f,0.f,0.f};

  float mst[2][4] = {{0.f,0.f,0.f,0.f},{0.f,0.f,0.f,0.f}};
  float lst[2][4] = {{1.f,1.f,1.f,1.f},{1.f,1.f,1.f,1.f}};

  const int krow = tid >> 2, ksh = krow >> 5, kr = krow & 31;
  const int kd0 = (tid & 3) * 32;
  const float* ksrc0 = (ksh ? kh1 : kh0) + kd0;
  const int vt = tid >> 3, vd = (tid & 7) * 16;

  const int nsteps = (qb + 64) / 32;
  for (int st = 0; st < nsteps; ++st) {
    const int kbt = st * 32;
    {
      const float* sp = ksrc0 + (size_t)(kbt + kr) * DH;
      #pragma unroll
      for (int c = 0; c < 4; ++c) {
        float4 f0 = *(const float4*)(sp + c*8);
        float4 f1 = *(const float4*)(sp + c*8 + 4);
        *(bf16x8*)&lds_k[ksh][kr][kd0 + c*8] = cvt8(f0, f1);
      }
      const float* vp = vh + (size_t)(kbt + vt) * DH + vd;
      #pragma unroll
      for (int c = 0; c < 4; ++c) {
        float4 f = *(const float4*)(vp + c*4);
        lds_vt[vd + c*4 + 0][vt] = (__bf16)f.x;
        lds_vt[vd + c*4 + 1][vt] = (__bf16)f.y;
        lds_vt[vd + c*4 + 2][vt] = (__bf16)f.z;
        lds_vt[vd + c*4 + 3][vt] = (__bf16)f.w;
      }
    }
    __syncthreads();

    f32x4 sacc[2][2];
    #pragma unroll
    for (int sh = 0; sh < 2; ++sh)
      #pragma unroll
      for (int n = 0; n < 2; ++n)
        sacc[sh][n] = (f32x4){0.f,0.f,0.f,0.f};

    #pragma unroll
    for (int sh = 0; sh < 2; ++sh)
      #pragma unroll
      for (int n = 0; n < 2; ++n)
        #pragma unroll
        for (int kd = 0; kd < 4; ++kd) {
          bf16x8 bf = *(const bf16x8*)&lds_k[sh][n*16 + l15][kd*32 + quad*8];
          sacc[sh][n] = __builtin_amdgcn_mfma_f32_16x16x32_bf16(qf[sh][kd], bf, sacc[sh][n], 0, 0, 0);
        }

    const int qrow0 = qb + w*16 + quad*4;
    const int c0 = kbt + l15, c1 = c0 + 16;
    #pragma unroll
    for (int sh = 0; sh < 2; ++sh) {
      #pragma unroll
      for (int r = 0; r < 4; ++r) {
        float s0 = sacc[sh][0][r] * SCALE;
        float s1 = sacc[sh][1][r] * SCALE;
        const int qr = qrow0 + r;
        if (c0 > qr) s0 = -1e30f;
        if (c1 > qr) s1 = -1e30f;
        float mx = fmaxf(s0, s1);
        #pragma unroll
        for (int off = 1; off < 16; off <<= 1)
          mx = fmaxf(mx, __shfl_xor(mx, off));
        const float mnew = fmaxf(mst[sh][r], mx);
        const float alpha = __expf(mst[sh][r] - mnew);
        mst[sh][r] = mnew;
        const float p0 = __expf(s0 - mnew);
        const float p1 = __expf(s1 - mnew);
        float rs = p0 + p1;
        #pragma unroll
        for (int off = 1; off < 16; off <<= 1)
          rs += __shfl_xor(rs, off);
        lst[sh][r] = lst[sh][r] * alpha + rs;
        #pragma unroll
        for (int nt = 0; nt < 8; ++nt)
          oacc[sh][nt][r] *= alpha;
        lds_p[w][sh][quad*4 + r][l15]      = (__bf16)p0;
        lds_p[w][sh][quad*4 + r][l15 + 16] = (__bf16)p1;
      }
    }

    {
      bf16x8 pf0 = *(const bf16x8*)&lds_p[w][0][l15][quad*8];
      bf16x8 pf1 = *(const bf16x8*)&lds_p[w][1][l15][quad*8];
      #pragma unroll
      for (int nt = 0; nt < 8; ++nt) {
        bf16x8 vf = *(const bf16x8*)&lds_vt[nt*16 + l15][quad*8];
        oacc[0][nt] = __builtin_amdgcn_mfma_f32_16x16x32_bf16(pf0, vf, oacc[0][nt], 0, 0, 0);
        oacc[1][nt] = __builtin_amdgcn_mfma_f32_16x16x32_bf16(pf1, vf, oacc[1][nt], 0, 0, 0);
      }
    }
    __syncthreads();
  }

  const int qrow0 = qb + w*16 + quad*4;
  float* obase = Obuf + (size_t)(b*NH + h) * SEQ * DH;
  float sum = 0.f, ss = 0.f;
  #pragma unroll
  for (int r = 0; r < 4; ++r) {
    const float i0 = 1.0f / lst[0][r];
    const float i1 = lam / lst[1][r];
    float* orow = obase + (size_t)(qrow0 + r) * DH + l15;
    #pragma unroll
    for (int nt = 0; nt < 8; ++nt) {
      const float val = oacc[0][nt][r] * i0 - oacc[1][nt][r] * i1;
      orow[nt*16] = val;
      sum += val;
      ss  += val * val;
    }
  }
  #pragma unroll
  for (int off = 1; off < 64; off <<= 1) {
    sum += __shfl_xor(sum, off);
    ss  += __shfl_xor(ss, off);
  }
  if (lane == 0) {
    atomicAdd(&stats[2*(b*NH + h)],     sum);
    atomicAdd(&stats[2*(b*NH + h) + 1], ss);
  }
}

// ---------------- GroupNorm epilogue ---------------------------------------
__global__ __launch_bounds__(256) void norm_kernel(
    float* __restrict__ Obuf, const float* __restrict__ stats,
    const float* __restrict__ gw, const float* __restrict__ gb)
{
  const int idx = (blockIdx.x * 256 + threadIdx.x) * 4;
  const int bh = idx >> 18;
  const int local = idx & 262143;
  const float inv = 1.0f / 262144.0f;
  const float mean = stats[2*bh] * inv;
  const float var  = stats[2*bh + 1] * inv - mean * mean;
  const float rstd = rsqrtf(var + 1e-5f);
  const int c = ((bh & 7) << 7) + (local >> 11);
  const float wq = gw[c] * rstd;
  const float bq = gb[c];
  float4 o = *(const float4*)(Obuf + idx);
  float4 r;
  r.x = ((o.x - mean) * wq + bq) * 0.2f;
  r.y = ((o.y - mean) * wq + bq) * 0.2f;
  r.z = ((o.z - mean) * wq + bq) * 0.2f;
  r.w = ((o.w - mean) * wq + bq) * 0.2f;
  *(float4*)(Obuf + idx) = r;
}

extern "C" void kernel_launch(void* const* d_in, const int* in_sizes, int n_in,
                              void* d_out, int out_size, void* d_ws, size_t ws_size,
                              hipStream_t stream) {
  const float* q   = (const float*)d_in[0];
  const float* k   = (const float*)d_in[1];
  const float* v   = (const float*)d_in[2];
  const float* lq1 = (const float*)d_in[3];
  const float* lk1 = (const float*)d_in[4];
  const float* lq2 = (const float*)d_in[5];
  const float* lk2 = (const float*)d_in[6];
  const float* gw  = (const float*)d_in[7];
  const float* gb  = (const float*)d_in[8];
  float* out = (float*)d_out;
  float* stats = (float*)d_ws;

  if (ws_size >= WS_NEED) {
    __bf16* Kb  = (__bf16*)((char*)d_ws + OFF_KB);
    __bf16* Vtb = (__bf16*)((char*)d_ws + OFF_VT);

    prep_kernel<<<8192, 256, 0, stream>>>(k, v, Kb, Vtb, stats);

    attn3_kernel<<<512, 512, 0, stream>>>(q, Kb, Vtb,
        lq1, lk1, lq2, lk2, out, stats);
  } else {
    (void)hipMemsetAsync(d_ws, 0, 256, stream);
    attn_fb_kernel<<<dim3(32, NH, 2), 256, 0, stream>>>(q, k, v,
        lq1, lk1, lq2, lk2, out, stats);
  }

  const int total = 2 * NH * SEQ * DH;
  norm_kernel<<<total / 1024, 256, 0, stream>>>(out, stats, gw, gb);
}